// Round 8
// baseline (117.668 us; speedup 1.0000x reference)
//
#include <hip/hip_runtime.h>
#include <hip/hip_bf16.h>

constexpr int Bb  = 4;
constexpr int Nn  = 1024;
constexpr int Fin = 256;
constexpr int Cc  = 256;   // H*HID
constexpr int Hh  = 8;
constexpr int Hid = 32;
constexpr float Alpha = 0.2f;
constexpr float L2E = 1.4426950408889634f;   // log2(e)
constexpr int NCHUNK = 16;                   // i-chunks for colsum partials

typedef __attribute__((ext_vector_type(8))) short bf16x8;
typedef __attribute__((ext_vector_type(4))) float f32x4;

__device__ __forceinline__ unsigned cvt_pk_bf16(float lo, float hi) {
    unsigned r;
    asm("v_cvt_pk_bf16_f32 %0, %1, %2" : "=v"(r) : "v"(lo), "v"(hi));
    return r;
}

// ---------------- K0: WT[c][k] = bf16(W[k][c]) for c<256; cols 256..271 = W@aL, W@aR (xL2E) ----
// grid (9,8): bx<8 transpose 32x32 tiles; bx==8 builds the 16 fused edge-dot columns.
__global__ __launch_bounds__(256) void k_wext(const float* __restrict__ W,
                                              const float* __restrict__ av,
                                              unsigned short* __restrict__ WT) {
    const int t = threadIdx.x;
    const int k0 = blockIdx.y * 32;
    if (blockIdx.x < 8) {
        __shared__ float tile[32][33];
        const int c0 = blockIdx.x * 32;
        {
            int kk = t >> 3, c4 = t & 7;
            float4 v = *reinterpret_cast<const float4*>(&W[(size_t)(k0 + kk) * Cc + c0 + c4 * 4]);
            tile[kk][c4 * 4 + 0] = v.x;
            tile[kk][c4 * 4 + 1] = v.y;
            tile[kk][c4 * 4 + 2] = v.z;
            tile[kk][c4 * 4 + 3] = v.w;
        }
        __syncthreads();
        int cc = t & 31, kq = t >> 5;
        float f0 = tile[kq * 4 + 0][cc], f1 = tile[kq * 4 + 1][cc];
        float f2 = tile[kq * 4 + 2][cc], f3 = tile[kq * 4 + 3][cc];
        uint2 pk = make_uint2(cvt_pk_bf16(f0, f1), cvt_pk_bf16(f2, f3));
        *reinterpret_cast<uint2*>(reinterpret_cast<char*>(WT) +
            (size_t)(c0 + cc) * 512 + (k0 + kq * 4) * 2) = pk;
    } else {
        int kk = t >> 3, c = t & 7;       // head c, k = k0+kk
        const float* wrow = &W[(size_t)(k0 + kk) * Cc + c * 32];
        float dl = 0.f, dr = 0.f;
        #pragma unroll
        for (int q = 0; q < 8; ++q) {
            float4 wv = *reinterpret_cast<const float4*>(&wrow[q * 4]);
            float4 al = *reinterpret_cast<const float4*>(&av[q * 4]);
            float4 ar = *reinterpret_cast<const float4*>(&av[32 + q * 4]);
            dl += wv.x * al.x + wv.y * al.y + wv.z * al.z + wv.w * al.w;
            dr += wv.x * ar.x + wv.y * ar.y + wv.z * ar.z + wv.w * ar.w;
        }
        dl *= L2E; dr *= L2E;
        WT[(size_t)(256 + c) * 256 + k0 + kk] = (unsigned short)(cvt_pk_bf16(dl, dl) & 0xFFFFu);
        WT[(size_t)(264 + c) * 256 + k0 + kk] = (unsigned short)(cvt_pk_bf16(dr, dr) & 0xFFFFu);
    }
}

// ---------------- K1: s = h @ W via MFMA; B-frags direct from WT; hp==4 emits ei/ej ----------
// grid (5, 64): hp 0..3 -> 64-col s tiles (sC fragment store); hp==4 -> 16 edge cols.
__global__ __launch_bounds__(256) void k_gemm(const float* __restrict__ hin,
                                              const unsigned short* __restrict__ WT,
                                              float* __restrict__ eiT,
                                              float* __restrict__ ejT,
                                              unsigned short* __restrict__ sC) {
    __shared__ unsigned short Asm[64 * 256];
    const int t = threadIdx.x;
    const int hp = blockIdx.x;
    const int rt = blockIdx.y;
    const int b = rt >> 4;
    const int row0m = (rt & 15) * 64;
    const int grow0 = rt * 64;

    // stage A: h rows -> bf16, 16B-quad XOR swizzle (2-way conflicts = free)
    #pragma unroll
    for (int i = 0; i < 16; ++i) {
        int fi = i * 256 + t;
        int r = fi >> 6, c4 = fi & 63;
        float4 v = *reinterpret_cast<const float4*>(&hin[(size_t)(grow0 + r) * Fin + c4 * 4]);
        uint2 pk = make_uint2(cvt_pk_bf16(v.x, v.y), cvt_pk_bf16(v.z, v.w));
        *reinterpret_cast<uint2*>(reinterpret_cast<char*>(Asm) + r * 512 +
            (((c4 >> 1) ^ ((r >> 1) & 7)) << 4) + ((c4 & 1) << 3)) = pk;
    }
    __syncthreads();

    const int w = t >> 6, l = t & 63;
    const int lr = l & 15, lg = l >> 4;
    const int ar = w * 16 + lr;

    if (hp < 4) {
        f32x4 acc[4] = {{0.f,0.f,0.f,0.f},{0.f,0.f,0.f,0.f},{0.f,0.f,0.f,0.f},{0.f,0.f,0.f,0.f}};
        #pragma unroll
        for (int ks = 0; ks < 8; ++ks) {
            bf16x8 af = *reinterpret_cast<const bf16x8*>(reinterpret_cast<char*>(Asm) +
                ar * 512 + ((((ks << 2) + lg) ^ ((ar >> 1) & 7)) << 4));
            #pragma unroll
            for (int n = 0; n < 4; ++n) {
                bf16x8 bf = *reinterpret_cast<const bf16x8*>(
                    &WT[(size_t)(hp * 64 + n * 16 + lr) * 256 + ks * 32 + lg * 8]);
                acc[n] = __builtin_amdgcn_mfma_f32_16x16x32_bf16(af, bf, acc[n], 0, 0, 0);
            }
        }
        const int jt16 = (row0m >> 4) + w;
        #pragma unroll
        for (int n = 0; n < 4; ++n) {
            int bh = b * 8 + hp * 2 + (n >> 1);
            uint2 pk = make_uint2(cvt_pk_bf16(acc[n][0], acc[n][1]),
                                  cvt_pk_bf16(acc[n][2], acc[n][3]));
            *reinterpret_cast<uint2*>(reinterpret_cast<char*>(sC) +
                ((((size_t)bh * 64 + jt16) * 2 + (n & 1)) * 64 + l) * 8) = pk;
        }
    } else {
        f32x4 acc = {0.f, 0.f, 0.f, 0.f};
        #pragma unroll
        for (int ks = 0; ks < 8; ++ks) {
            bf16x8 af = *reinterpret_cast<const bf16x8*>(reinterpret_cast<char*>(Asm) +
                ar * 512 + ((((ks << 2) + lg) ^ ((ar >> 1) & 7)) << 4));
            bf16x8 bf = *reinterpret_cast<const bf16x8*>(
                &WT[(size_t)(256 + lr) * 256 + ks * 32 + lg * 8]);
            acc = __builtin_amdgcn_mfma_f32_16x16x32_bf16(af, bf, acc, 0, 0, 0);
        }
        const int rowg = row0m + w * 16 + lg * 4;
        if (lr < 8) {
            #pragma unroll
            for (int reg = 0; reg < 4; ++reg)
                eiT[(size_t)(b * 8 + lr) * Nn + rowg + reg] = acc[reg];
        } else {
            #pragma unroll
            for (int reg = 0; reg < 4; ++reg)
                ejT[(size_t)(b * 8 + lr - 8) * Nn + rowg + reg] = acc[reg];
        }
    }
}

// ---------------- K2: column sums Zp[ic][bh][j] + transposed adjacency bitmask ----------------
__global__ __launch_bounds__(256) void k_colsum(const float* __restrict__ eiT,
                                                const float* __restrict__ ejT,
                                                const int* __restrict__ adj,
                                                float* __restrict__ Zp,
                                                unsigned long long* __restrict__ adjBT) {
    const int ic = blockIdx.x;
    const int jt = blockIdx.y;
    const int b  = blockIdx.z;
    const int i0 = ic * 64;
    const int j0 = jt * 64;
    const int t = threadIdx.x;
    const int jj = t & 63;
    const int g = t >> 6;
    __shared__ float eis[64 * Hh];         // [i][h]
    __shared__ float red[4 * 64 * Hh];     // [g][jj][h]
    for (int v = t; v < 64 * Hh; v += 256) {
        int h = v >> 6, i = v & 63;
        eis[i * Hh + h] = eiT[((size_t)b * Hh + h) * Nn + i0 + i];
    }
    float ejr[Hh];
    #pragma unroll
    for (int hh = 0; hh < Hh; ++hh)
        ejr[hh] = ejT[((size_t)b * Hh + hh) * Nn + j0 + jj];
    __syncthreads();
    float z[Hh] = {};
    const int* ap = &adj[((size_t)b * Nn + i0 + g * 16) * Nn + j0 + jj];
    #pragma unroll 4
    for (int ii = 0; ii < 16; ++ii) {
        int a = ap[(size_t)ii * Nn];
        unsigned long long bal = __ballot(a != 0);
        if (jj == 0)
            adjBT[((size_t)b * 16 + jt) * Nn + (i0 + g * 16 + ii)] = bal;
        float mf = (float)(a != 0);
        const float* ep = &eis[(g * 16 + ii) * Hh];
        #pragma unroll
        for (int hh = 0; hh < Hh; ++hh) {
            float x = ep[hh] + ejr[hh];
            x = fmaxf(x, Alpha * x);
            z[hh] = fmaf(mf, exp2f(x), z[hh]);
        }
    }
    #pragma unroll
    for (int hh = 0; hh < Hh; ++hh)
        red[(g * 64 + jj) * Hh + hh] = z[hh];
    __syncthreads();
    // write Zp in [ic][b*8+h][j] layout -> k_agg's fold reads are coalesced
    for (int v = t; v < 64 * Hh; v += 256) {
        int h2 = v >> 6, jj2 = v & 63;
        float sum = red[jj2 * Hh + h2] + red[(64 + jj2) * Hh + h2] +
                    red[(128 + jj2) * Hh + h2] + red[(192 + jj2) * Hh + h2];
        Zp[(size_t)ic * (Bb * Nn * Hh) + ((size_t)b * Hh + h2) * Nn + j0 + jj2] = sum;
    }
}

// ---------------- K3: MFMA aggregation: out = (E.rz) @ s_bf16 + bias (Z-fold in LDS) --------
__global__ __launch_bounds__(256) void k_agg(const unsigned short* __restrict__ sC,
                                             const float* __restrict__ eiT,
                                             const float* __restrict__ ejT,
                                             const float* __restrict__ Zp,
                                             const unsigned long long* __restrict__ adjBT,
                                             const float* __restrict__ bias,
                                             float* __restrict__ out) {
    const int bid = blockIdx.x;
    const int xcd = bid & 7, g = bid >> 3;
    const int bh = xcd * 4 + (g & 3);
    const int it = g >> 2;
    const int b = bh >> 3, h = bh & 7;
    const int t = threadIdx.x, w = t >> 6, l = t & 63;
    const int lg = l >> 4;
    const int row = it * 64 + w * 16 + (l & 15);

    __shared__ __align__(16) float2 ez_s[Nn];   // {ej, 1/Z} per j
    #pragma unroll
    for (int q = 0; q < 4; ++q) {
        int j = q * 256 + t;
        float sum = 0.f;
        #pragma unroll
        for (int c = 0; c < NCHUNK; ++c)
            sum += Zp[(size_t)c * (Bb * Nn * Hh) + (size_t)bh * Nn + j];
        ez_s[j] = make_float2(ejT[(size_t)bh * Nn + j], 1.0f / sum);
    }
    __syncthreads();

    const float ei_r = eiT[(size_t)bh * Nn + row];
    const float4* ez4 = reinterpret_cast<const float4*>(ez_s);
    const unsigned long long* scp =
        reinterpret_cast<const unsigned long long*>(sC) + (size_t)bh * 8192;
    const int lpos = ((l >> 4) & 1) * 32 + (l & 15);

    f32x4 acc0 = {0.f, 0.f, 0.f, 0.f}, acc1 = {0.f, 0.f, 0.f, 0.f};

    for (int jk = 0; jk < 32; ++jk) {
        const int j8 = jk * 32 + lg * 8;
        float4 za = ez4[(j8 >> 1) + 0];
        float4 zb = ez4[(j8 >> 1) + 1];
        float4 zc = ez4[(j8 >> 1) + 2];
        float4 zd = ez4[(j8 >> 1) + 3];
        unsigned long long m64 = adjBT[((size_t)b * 16 + (jk >> 1)) * Nn + row];
        unsigned mb = (unsigned)(m64 >> ((jk & 1) * 32 + lg * 8)) & 0xFFu;

        float wv[8];
        {
            float ejv[8] = {za.x, za.z, zb.x, zb.z, zc.x, zc.z, zd.x, zd.z};
            float rzv[8] = {za.y, za.w, zb.y, zb.w, zc.y, zc.w, zd.y, zd.w};
            #pragma unroll
            for (int e = 0; e < 8; ++e) {
                float x = ei_r + ejv[e];
                x = fmaxf(x, Alpha * x);
                float ww = exp2f(x) * rzv[e];
                wv[e] = ((mb >> e) & 1u) ? ww : 0.0f;
            }
        }
        union { bf16x8 v; unsigned u[4]; } A;
        A.u[0] = cvt_pk_bf16(wv[0], wv[1]);
        A.u[1] = cvt_pk_bf16(wv[2], wv[3]);
        A.u[2] = cvt_pk_bf16(wv[4], wv[5]);
        A.u[3] = cvt_pk_bf16(wv[6], wv[7]);

        const int j16 = jk * 2 + (l >> 5);
        union { bf16x8 v; unsigned long long q[2]; } B0, B1;
        const unsigned long long* p0 = scp + ((size_t)j16 * 2 + 0) * 64 + lpos;
        const unsigned long long* p1 = scp + ((size_t)j16 * 2 + 1) * 64 + lpos;
        B0.q[0] = p0[0];  B0.q[1] = p0[16];
        B1.q[0] = p1[0];  B1.q[1] = p1[16];

        acc0 = __builtin_amdgcn_mfma_f32_16x16x32_bf16(A.v, B0.v, acc0, 0, 0, 0);
        acc1 = __builtin_amdgcn_mfma_f32_16x16x32_bf16(A.v, B1.v, acc1, 0, 0, 0);
    }

    const int col = l & 15;
    const float bv0 = bias[h * Hid + col];
    const float bv1 = bias[h * Hid + 16 + col];
    const int r0 = it * 64 + w * 16 + lg * 4;
    #pragma unroll
    for (int reg = 0; reg < 4; ++reg) {
        float* op = &out[((size_t)b * Nn + r0 + reg) * Cc + h * Hid];
        op[col]      = acc0[reg] + bv0;
        op[16 + col] = acc1[reg] + bv1;
    }
}

extern "C" void kernel_launch(void* const* d_in, const int* in_sizes, int n_in,
                              void* d_out, int out_size, void* d_ws, size_t ws_size,
                              hipStream_t stream) {
    const float* hin  = (const float*)d_in[0];
    const int*   adj  = (const int*)d_in[1];
    const float* W    = (const float*)d_in[2];
    const float* a    = (const float*)d_in[3];
    const float* bias = (const float*)d_in[4];
    float* out = (float*)d_out;
    float* ws  = (float*)d_ws;

    float* eiT = ws;                                      // 32,768 f32
    float* ejT = ws + 32768;                              // 32,768 f32
    float* Zp  = ws + 65536;                              // 16 x 32,768 f32
    unsigned short* WT = (unsigned short*)(ws + 589824);  // 272*256 bf16
    unsigned long long* adjBT = (unsigned long long*)(ws + 624640);  // 65,536 u64
    unsigned short* sC = (unsigned short*)(ws + 755712);  // 1,048,576 bf16

    k_wext  <<<dim3(9, 8),       256, 0, stream>>>(W, a, WT);
    k_gemm  <<<dim3(5, 64),      256, 0, stream>>>(hin, WT, eiT, ejT, sC);
    k_colsum<<<dim3(16, 16, 4),  256, 0, stream>>>(eiT, ejT, adj, Zp, adjBT);
    k_agg   <<<dim3(512),        256, 0, stream>>>(sC, eiT, ejT, Zp, adjBT, bias, out);
}